// Round 7
// baseline (7350.993 us; speedup 1.0000x reference)
//
#include <hip/hip_runtime.h>
#include <hip/hip_bf16.h>
#include <hip/hip_cooperative_groups.h>
#include <math.h>
#include <float.h>

namespace cg = cooperative_groups;

// Problem dims
#define BDIM   64
#define PDIM   196
#define ENC    2048
#define DECD   512
#define ATTD   512
#define EMBD   512
#define VOC    10000
#define LCAP   30
#define TSTEPS 29

typedef __attribute__((ext_vector_type(8))) short s8v;   // 8 x bf16
typedef __attribute__((ext_vector_type(4))) float f4v;   // MFMA acc

__device__ __forceinline__ float sigf(float x) { return 1.0f / (1.0f + expf(-x)); }
__device__ __forceinline__ float bf2f(ushort u) { return __uint_as_float(((uint)u) << 16); }

// ---------------------------------------------------------------------------
// Pipelined MFMA K-segment: NIT iterations of k+=32, 3-slot rotation, depth 2.
// ---------------------------------------------------------------------------
template <int MF, int NF, int NIT>
__device__ __forceinline__ void gemm_seg(const __hip_bfloat16* const* arow,
                                         const __hip_bfloat16* const* wrow,
                                         f4v acc[][NF]) {
    s8v aP[3][MF], bP[3][NF];
    auto LD = [&](int it, int slot) {
#pragma unroll
        for (int mi = 0; mi < MF; ++mi) aP[slot][mi] = *(const s8v*)(arow[mi] + it * 32);
#pragma unroll
        for (int ni = 0; ni < NF; ++ni) bP[slot][ni] = *(const s8v*)(wrow[ni] + it * 32);
    };
    LD(0, 0);
    if constexpr (NIT > 1) LD(1, 1);
#pragma unroll
    for (int it = 0; it < NIT; ++it) {
        if (it + 2 < NIT) LD(it + 2, (it + 2) % 3);
        const int s = it % 3;
#pragma unroll
        for (int mi = 0; mi < MF; ++mi)
#pragma unroll
            for (int ni = 0; ni < NF; ++ni)
                acc[mi][ni] = __builtin_amdgcn_mfma_f32_16x16x32_bf16(aP[s][mi], bP[s][ni], acc[mi][ni], 0, 0, 0);
    }
}

// ===========================================================================
// Decode phase device functions (shared by cooperative kernel AND fallback)
// ===========================================================================

// P1: C_h[64][4608] = h @ [W_beta(2048)|W_dec(512)|W_hh(2048)]^T  (K=512)
// bid in [0,72): n-tile. wave w = m-tile (16 rows).
__device__ __forceinline__ void phase1(int bid, int tid,
    const __hip_bfloat16* hbuf, const __hip_bfloat16* Wb_bet,
    const __hip_bfloat16* Wb_dec, const __hip_bfloat16* Wb_hh, float* C_h) {
    const int l = tid & 63, c16 = l & 15, kg = l >> 4, w = tid >> 6;
    const int n0 = bid * 64;
    f4v acc[1][4];
#pragma unroll
    for (int ni = 0; ni < 4; ++ni) acc[0][ni] = (f4v)0.0f;
    const __hip_bfloat16* arow[1] = { hbuf + (size_t)(w * 16 + c16) * 512 + kg * 8 };
    const __hip_bfloat16* wrow[4];
#pragma unroll
    for (int ni = 0; ni < 4; ++ni) {
        int n = n0 + ni * 16 + c16;
        const __hip_bfloat16* wr;
        if (n < 2048)      wr = Wb_bet + (size_t)n * 512;
        else if (n < 2560) wr = Wb_dec + (size_t)(n - 2048) * 512;
        else               wr = Wb_hh + (size_t)(n - 2560) * 512;
        wrow[ni] = wr + kg * 8;
    }
    gemm_seg<1, 4, 16>(arow, wrow, acc);
#pragma unroll
    for (int ni = 0; ni < 4; ++ni)
#pragma unroll
        for (int i = 0; i < 4; ++i)
            C_h[(size_t)(w * 16 + kg * 4 + i) * 4608 + n0 + ni * 16 + c16] = acc[0][ni][i];
}

// P2: per (b = bid>>2, q = bid&3): e-scores + softmax (redundant per q),
// gated awe over cols [q*512,(q+1)*512) -> awebuf; alphas out at q==0.
__device__ __forceinline__ void phase2(int bid, int tid, float* smem,
    const __hip_bfloat16* att1, const __hip_bfloat16* enc_s, const float* C_h,
    const float* w_full, const float* b_full, const float* b_dec,
    const float* b_beta, const int* dec_lens,
    __hip_bfloat16* awebuf, float* out_alphas, int t) {
    const int b = bid >> 2, q = bid & 3;
    const int l = tid & 63, w = tid >> 6;
    float* s_att2 = smem;            // [0,512)
    float* s_wf   = smem + 512;      // [512,1024)
    float* s_e    = smem + 1024;     // [1024,1280)
    float* red    = smem + 1280;     // [1280,1536)
    float* s_part = smem + 1536;     // [1536,3584)

    s_att2[tid]       = C_h[(size_t)b * 4608 + 2048 + tid]       + b_dec[tid];
    s_att2[tid + 256] = C_h[(size_t)b * 4608 + 2048 + 256 + tid] + b_dec[256 + tid];
    s_wf[tid]       = w_full[tid];
    s_wf[tid + 256] = w_full[tid + 256];
    __syncthreads();

    // e-scores (all q compute all 196 identically; wave w does p = w mod 4)
    const float bf = b_full[0];
    const int a0 = l << 3;
    for (int p = w; p < PDIM; p += 4) {
        const ushort* row = (const ushort*)att1 + ((size_t)b * PDIM + p) * 512 + a0;
        s8v u = *(const s8v*)row;
        float s = 0.f;
#pragma unroll
        for (int i = 0; i < 8; ++i) {
            float x = bf2f((ushort)u[i]) + s_att2[a0 + i];
            s += fmaxf(x, 0.f) * s_wf[a0 + i];
        }
#pragma unroll
        for (int off = 32; off; off >>= 1) s += __shfl_xor(s, off);
        if (l == 0) s_e[p] = s + bf;
    }
    __syncthreads();

    // softmax over 196 (alpha stays in s_e)
    float v = (tid < PDIM) ? s_e[tid] : -FLT_MAX;
    red[tid] = v;
    __syncthreads();
    for (int st = 128; st; st >>= 1) {
        if (tid < st) red[tid] = fmaxf(red[tid], red[tid + st]);
        __syncthreads();
    }
    float mx = red[0];
    __syncthreads();
    float ex = (tid < PDIM) ? expf(v - mx) : 0.f;
    red[tid] = ex;
    __syncthreads();
    for (int st = 128; st; st >>= 1) {
        if (tid < st) red[tid] += red[tid + st];
        __syncthreads();
    }
    float inv = 1.f / red[0];
    __syncthreads();
    if (tid < PDIM) {
        float al = ex * inv;
        s_e[tid] = al;
        if (q == 0)
            out_alphas[(size_t)b * (TSTEPS * PDIM) + (size_t)t * PDIM + tid] =
                (t < dec_lens[b]) ? al : 0.f;
    }
    __syncthreads();

    // awe: wave w sums its 49 p-rows over this block's 512-col slice
    const int c0 = q * 512 + l * 8;
    const ushort* ep = (const ushort*)enc_s + (size_t)b * (PDIM * ENC) + c0;
    float a8[8];
#pragma unroll
    for (int i = 0; i < 8; ++i) a8[i] = 0.f;
    for (int p = w * 49; p < w * 49 + 49; ++p) {
        float al = s_e[p];
        s8v u = *(const s8v*)(ep + (size_t)p * ENC);
#pragma unroll
        for (int i = 0; i < 8; ++i) a8[i] += al * bf2f((ushort)u[i]);
    }
#pragma unroll
    for (int i = 0; i < 8; ++i) s_part[w * 512 + l * 8 + i] = a8[i];
    __syncthreads();
#pragma unroll
    for (int u2 = 0; u2 < 2; ++u2) {
        int cc = tid * 2 + u2;
        float s = s_part[cc] + s_part[512 + cc] + s_part[1024 + cc] + s_part[1536 + cc];
        int gcol = q * 512 + cc;
        float gate = sigf(C_h[(size_t)b * 4608 + gcol] + b_beta[gcol]);
        awebuf[(size_t)b * 2048 + gcol] = __float2bfloat16(s * gate);
    }
}

// P3: gates = emb@W_ihE^T + awe@W_ihA^T + C_h(hh) + biases -> LSTM cell.
// bid in [0,32): j-slice of 16. Wave w = gate w (full K per wave, no split-K).
__device__ __forceinline__ void phase3(int bid, int tid, float* smem,
    const __hip_bfloat16* awebuf, const __hip_bfloat16* embs_all,
    const __hip_bfloat16* Wb_ih, const float* C_h,
    const float* b_ih, const float* b_hh,
    float* cbuf, __hip_bfloat16* hbuf, __hip_bfloat16* hstore, int t) {
    const int l = tid & 63, c16 = l & 15, kg = l >> 4, w = tid >> 6;
    const int j0 = bid * 16;
    f4v acc[4][1];
#pragma unroll
    for (int mi = 0; mi < 4; ++mi) acc[mi][0] = (f4v)0.0f;
    const __hip_bfloat16* arow[4];
    const __hip_bfloat16* wrow[1];
    const __hip_bfloat16* wbase = Wb_ih + (size_t)(512 * w + j0 + c16) * 2560;
    // emb segment: W_ih cols [0,512)
#pragma unroll
    for (int mi = 0; mi < 4; ++mi)
        arow[mi] = embs_all + ((size_t)t * 64 + mi * 16 + c16) * 512 + kg * 8;
    wrow[0] = wbase + kg * 8;
    gemm_seg<4, 1, 16>(arow, wrow, acc);
    // awe segment: W_ih cols [512,2560)
#pragma unroll
    for (int mi = 0; mi < 4; ++mi)
        arow[mi] = awebuf + (size_t)(mi * 16 + c16) * 2048 + kg * 8;
    wrow[0] = wbase + 512 + kg * 8;
    gemm_seg<4, 1, 64>(arow, wrow, acc);
    // dump: smem[gate w][64 rows][16 cols]
#pragma unroll
    for (int mi = 0; mi < 4; ++mi)
#pragma unroll
        for (int i = 0; i < 4; ++i)
            smem[w * 1024 + (mi * 16 + kg * 4 + i) * 16 + c16] = acc[mi][0][i];
    __syncthreads();
    // cell: 1024 (b,jj) pairs over 4 iterations
#pragma unroll
    for (int u2 = 0; u2 < 4; ++u2) {
        int pid = u2 * 256 + tid;
        int b = pid >> 4, jj = pid & 15;
        float vg[4];
#pragma unroll
        for (int g = 0; g < 4; ++g) {
            int col = 512 * g + j0 + jj;
            vg[g] = smem[g * 1024 + b * 16 + jj]
                  + C_h[(size_t)b * 4608 + 2560 + col]
                  + b_ih[col] + b_hh[col];
        }
        float i_ = sigf(vg[0]), f_ = sigf(vg[1]), gg = tanhf(vg[2]), o_ = sigf(vg[3]);
        int cidx = b * 512 + j0 + jj;
        float cn = f_ * cbuf[cidx] + i_ * gg;
        cbuf[cidx] = cn;
        __hip_bfloat16 hb = __float2bfloat16(o_ * tanhf(cn));
        hbuf[cidx] = hb;
        hstore[(size_t)t * (64 * 512) + cidx] = hb;
    }
}

// ---------------------------------------------------------------------------
// Cooperative persistent decode: 256 blocks x 256 threads, 16KB LDS.
// ---------------------------------------------------------------------------
__global__ __launch_bounds__(256) void decode_kernel(
    const __hip_bfloat16* att1, const __hip_bfloat16* enc_s,
    const __hip_bfloat16* embs_all, const __hip_bfloat16* Wb_bet,
    const __hip_bfloat16* Wb_dec, const __hip_bfloat16* Wb_hh,
    const __hip_bfloat16* Wb_ih, const float* b_dec, const float* b_beta,
    const float* b_full, const float* w_full, const float* b_ih,
    const float* b_hh, const int* dec_lens, __hip_bfloat16* hbuf,
    float* cbuf, float* C_h, __hip_bfloat16* awebuf,
    __hip_bfloat16* hstore, float* out_alphas) {
    cg::grid_group grid = cg::this_grid();
    __shared__ float smem[4096];
    const int tid = threadIdx.x, bid = blockIdx.x;
#pragma unroll 1
    for (int t = 0; t < TSTEPS; ++t) {
        if (bid < 72) phase1(bid, tid, hbuf, Wb_bet, Wb_dec, Wb_hh, C_h);
        grid.sync();
        phase2(bid, tid, smem, att1, enc_s, C_h, w_full, b_full, b_dec, b_beta,
               dec_lens, awebuf, out_alphas, t);
        grid.sync();
        if (bid < 32) phase3(bid, tid, smem, awebuf, embs_all, Wb_ih, C_h,
                             b_ih, b_hh, cbuf, hbuf, hstore, t);
        grid.sync();
    }
}

// Fallback per-phase kernels (regular launches) — same device code.
__global__ __launch_bounds__(256) void p1_kernel(
    const __hip_bfloat16* hbuf, const __hip_bfloat16* Wb_bet,
    const __hip_bfloat16* Wb_dec, const __hip_bfloat16* Wb_hh, float* C_h) {
    phase1(blockIdx.x, threadIdx.x, hbuf, Wb_bet, Wb_dec, Wb_hh, C_h);
}
__global__ __launch_bounds__(256) void p2_kernel(
    const __hip_bfloat16* att1, const __hip_bfloat16* enc_s, const float* C_h,
    const float* w_full, const float* b_full, const float* b_dec,
    const float* b_beta, const int* dec_lens,
    __hip_bfloat16* awebuf, float* out_alphas, int t) {
    __shared__ float smem[4096];
    phase2(blockIdx.x, threadIdx.x, smem, att1, enc_s, C_h, w_full, b_full,
           b_dec, b_beta, dec_lens, awebuf, out_alphas, t);
}
__global__ __launch_bounds__(256) void p3_kernel(
    const __hip_bfloat16* awebuf, const __hip_bfloat16* embs_all,
    const __hip_bfloat16* Wb_ih, const float* C_h,
    const float* b_ih, const float* b_hh,
    float* cbuf, __hip_bfloat16* hbuf, __hip_bfloat16* hstore, int t) {
    __shared__ float smem[4096];
    phase3(blockIdx.x, threadIdx.x, smem, awebuf, embs_all, Wb_ih, C_h,
           b_ih, b_hh, cbuf, hbuf, hstore, t);
}

// ===========================================================================
// Init-phase kernels
// ===========================================================================
__global__ void sort_kernel(const int* __restrict__ cap_len,
                            const int* __restrict__ caps,
                            int* __restrict__ sort_ind,
                            int* __restrict__ dec_lens,
                            int* __restrict__ caps_s,
                            float* __restrict__ out_caps,
                            float* __restrict__ out_dlen,
                            float* __restrict__ out_sind) {
    int i = threadIdx.x;  // 64 threads
    __shared__ int len[BDIM];
    len[i] = cap_len[i];
    __syncthreads();
    int li = len[i];
    int r = 0;
    for (int j = 0; j < BDIM; ++j) {
        int lj = len[j];
        if (lj > li || (lj == li && j < i)) ++r;
    }
    sort_ind[r] = i;
    dec_lens[r] = li - 1;
    out_sind[r] = (float)i;
    out_dlen[r] = (float)(li - 1);
    for (int tt = 0; tt < LCAP; ++tt) {
        int v = caps[i * LCAP + tt];
        caps_s[r * LCAP + tt] = v;
        out_caps[r * LCAP + tt] = (float)v;
    }
}

__global__ __launch_bounds__(256) void conv_enc_kernel(const float* __restrict__ enc,
                                                       const int* __restrict__ sort_ind,
                                                       __hip_bfloat16* __restrict__ enc_s,
                                                       float* __restrict__ mean_enc) {
    int b = blockIdx.y, tid = threadIdx.x;
    int e = (blockIdx.x << 8) + tid;
    const float* ep = enc + (size_t)sort_ind[b] * (PDIM * ENC) + e;
    __hip_bfloat16* op = enc_s + (size_t)b * (PDIM * ENC) + e;
    float s = 0.f;
    for (int p = 0; p < PDIM; ++p) {
        float v = ep[(size_t)p * ENC];
        s += v;
        op[(size_t)p * ENC] = __float2bfloat16(v);
    }
    mean_enc[(size_t)b * ENC + e] = s * (1.0f / (float)PDIM);
}

__global__ __launch_bounds__(256) void f2b_kernel(const float* __restrict__ src,
                                                  __hip_bfloat16* __restrict__ dst, int n) {
    int i = blockIdx.x * 256 + threadIdx.x;
    if (i < n) dst[i] = __float2bfloat16(src[i]);
}

__global__ __launch_bounds__(256) void h0b_kernel(const float* __restrict__ h0f,
                                                  __hip_bfloat16* __restrict__ hbuf) {
    int idx = blockIdx.x * 256 + threadIdx.x;  // < 64*512
    hbuf[idx] = __float2bfloat16(h0f[idx]);
}

__global__ __launch_bounds__(256) void embgather_kernel(
    const float* __restrict__ emb_table, const int* __restrict__ caps_s,
    __hip_bfloat16* __restrict__ embs_all) {
    int b = blockIdx.x, t = blockIdx.y;
    int cap = caps_s[b * LCAP + t];
    int j = threadIdx.x << 1;
    float2 e = *(const float2*)(emb_table + (size_t)cap * EMBD + j);
    __hip_bfloat16 eb[2];
    eb[0] = __float2bfloat16(e.x); eb[1] = __float2bfloat16(e.y);
    *(uint*)(embs_all + ((size_t)t * 64 + b) * 512 + j) = *(uint*)eb;
}

__global__ __launch_bounds__(256) void gemm32_k(
    const float* __restrict__ A, int lda,
    const float* __restrict__ W0, const float* __restrict__ bias0,
    float* __restrict__ C, int ldc, int K) {
    __shared__ float As[16][64];
    __shared__ float Ws[16][64];
    const int tid = threadIdx.x;
    const int tx = tid & 15, ty = tid >> 4;
    const int bn0 = blockIdx.x * 64;
    const int lr = tid >> 2;
    const int lk = (tid & 3) << 2;
    const float* Arow = A + (size_t)lr * lda;
    const int wn = bn0 + lr;
    float acc[4][4];
#pragma unroll
    for (int i = 0; i < 4; ++i)
#pragma unroll
        for (int j = 0; j < 4; ++j) acc[i][j] = 0.f;
    for (int k0 = 0; k0 < K; k0 += 16) {
        float4 av = *(const float4*)(Arow + k0 + lk);
        float4 wv = *(const float4*)(W0 + (size_t)wn * K + k0 + lk);
        __syncthreads();
        As[lk + 0][lr] = av.x; As[lk + 1][lr] = av.y;
        As[lk + 2][lr] = av.z; As[lk + 3][lr] = av.w;
        Ws[lk + 0][lr] = wv.x; Ws[lk + 1][lr] = wv.y;
        Ws[lk + 2][lr] = wv.z; Ws[lk + 3][lr] = wv.w;
        __syncthreads();
#pragma unroll
        for (int kk = 0; kk < 16; ++kk) {
            const float4 a = *(const float4*)&As[kk][ty << 2];
            const float4 w = *(const float4*)&Ws[kk][tx << 2];
            acc[0][0] += a.x * w.x; acc[0][1] += a.x * w.y; acc[0][2] += a.x * w.z; acc[0][3] += a.x * w.w;
            acc[1][0] += a.y * w.x; acc[1][1] += a.y * w.y; acc[1][2] += a.y * w.z; acc[1][3] += a.y * w.w;
            acc[2][0] += a.z * w.x; acc[2][1] += a.z * w.y; acc[2][2] += a.z * w.z; acc[2][3] += a.z * w.w;
            acc[3][0] += a.w * w.x; acc[3][1] += a.w * w.y; acc[3][2] += a.w * w.z; acc[3][3] += a.w * w.w;
        }
    }
#pragma unroll
    for (int i = 0; i < 4; ++i) {
        int row = (ty << 2) + i;
#pragma unroll
        for (int j = 0; j < 4; ++j) {
            int col = bn0 + (tx << 2) + j;
            C[(size_t)row * ldc + col] = acc[i][j] + bias0[col];
        }
    }
}

__global__ __launch_bounds__(64) void att1_gemm(
    const __hip_bfloat16* __restrict__ A, const __hip_bfloat16* __restrict__ W,
    const float* __restrict__ bias, __hip_bfloat16* __restrict__ C) {
    const int l = threadIdx.x, c16 = l & 15, kg = l >> 4;
    const int m0 = blockIdx.x * 64, n0 = blockIdx.y * 64;
    f4v acc[4][4];
#pragma unroll
    for (int mi = 0; mi < 4; ++mi)
#pragma unroll
        for (int ni = 0; ni < 4; ++ni) acc[mi][ni] = (f4v)0.0f;
    const __hip_bfloat16* arow[4];
#pragma unroll
    for (int mi = 0; mi < 4; ++mi)
        arow[mi] = A + (size_t)(m0 + mi * 16 + c16) * ENC + kg * 8;
    const __hip_bfloat16* wrow[4];
#pragma unroll
    for (int ni = 0; ni < 4; ++ni)
        wrow[ni] = W + (size_t)(n0 + ni * 16 + c16) * ENC + kg * 8;
    gemm_seg<4, 4, 64>(arow, wrow, acc);
#pragma unroll
    for (int mi = 0; mi < 4; ++mi)
#pragma unroll
        for (int ni = 0; ni < 4; ++ni)
#pragma unroll
            for (int i = 0; i < 4; ++i) {
                int r = m0 + mi * 16 + kg * 4 + i;
                int c = n0 + ni * 16 + c16;
                C[(size_t)r * 512 + c] = __float2bfloat16(acc[mi][ni][i] + bias[c]);
            }
}

__global__ __launch_bounds__(64) void predsb_gemm(
    const __hip_bfloat16* __restrict__ Hs,   // [1856][512]
    const __hip_bfloat16* __restrict__ Wfc,  // [10000][512]
    const float* __restrict__ bias,
    const int* __restrict__ dec_lens,
    float* __restrict__ out) {
    const int l = threadIdx.x, c16 = l & 15, kg = l >> 4;
    const int n0 = blockIdx.x * 64, m0 = blockIdx.y * 32;
    f4v acc[2][4];
#pragma unroll
    for (int mi = 0; mi < 2; ++mi)
#pragma unroll
        for (int ni = 0; ni < 4; ++ni) acc[mi][ni] = (f4v)0.0f;
    const __hip_bfloat16* arow[2];
#pragma unroll
    for (int mi = 0; mi < 2; ++mi)
        arow[mi] = Hs + (size_t)(m0 + mi * 16 + c16) * 512 + kg * 8;
    const __hip_bfloat16* wrow[4];
#pragma unroll
    for (int ni = 0; ni < 4; ++ni) {
        int n = n0 + ni * 16 + c16;
        int nn = (n < VOC) ? n : (VOC - 1);
        wrow[ni] = Wfc + (size_t)nn * 512 + kg * 8;
    }
    gemm_seg<2, 4, 16>(arow, wrow, acc);
#pragma unroll
    for (int mi = 0; mi < 2; ++mi)
#pragma unroll
        for (int ni = 0; ni < 4; ++ni)
#pragma unroll
            for (int i = 0; i < 4; ++i) {
                int r = m0 + mi * 16 + kg * 4 + i;
                int c = n0 + ni * 16 + c16;
                if (c < VOC) {
                    int tt = r >> 6, b = r & 63;
                    float v = acc[mi][ni][i] + bias[c];
                    out[(size_t)b * (TSTEPS * VOC) + (size_t)tt * VOC + c] =
                        (tt < dec_lens[b]) ? v : 0.f;
                }
            }
}

// ---------------------------------------------------------------------------
extern "C" void kernel_launch(void* const* d_in, const int* in_sizes, int n_in,
                              void* d_out, int out_size, void* d_ws, size_t ws_size,
                              hipStream_t stream) {
    const float* enc      = (const float*)d_in[0];
    const int*   caps     = (const int*)d_in[1];
    const int*   clen     = (const int*)d_in[2];
    const float* W_enc    = (const float*)d_in[3];
    const float* b_enc    = (const float*)d_in[4];
    const float* W_dec    = (const float*)d_in[5];
    const float* b_dec    = (const float*)d_in[6];
    const float* w_full   = (const float*)d_in[7];
    const float* b_full   = (const float*)d_in[8];
    const float* emb_tab  = (const float*)d_in[9];
    const float* W_ih     = (const float*)d_in[10];
    const float* b_ih     = (const float*)d_in[11];
    const float* W_hh     = (const float*)d_in[12];
    const float* b_hh     = (const float*)d_in[13];
    const float* W_init_h = (const float*)d_in[14];
    const float* b_init_h = (const float*)d_in[15];
    const float* W_init_c = (const float*)d_in[16];
    const float* b_init_c = (const float*)d_in[17];
    const float* W_beta   = (const float*)d_in[18];
    const float* b_beta   = (const float*)d_in[19];
    const float* W_fc     = (const float*)d_in[20];
    const float* b_fc     = (const float*)d_in[21];

    float* out_pred = (float*)d_out;
    float* out_alph = out_pred + (size_t)BDIM * TSTEPS * VOC;
    float* out_caps = out_alph + (size_t)BDIM * TSTEPS * PDIM;
    float* out_dlen = out_caps + BDIM * LCAP;
    float* out_sind = out_dlen + BDIM;

    // ---- workspace carve-up (256B aligned, NO lifetime aliasing of hstore) --
    char* p = (char*)d_ws;
    auto carve = [&](size_t bytes) { char* r = p; p += (bytes + 255) & ~(size_t)255; return r; };
    int* sort_ind = (int*)carve(64 * 4);
    int* dec_lens = (int*)carve(64 * 4);
    int* caps_s   = (int*)carve(64 * LCAP * 4);
    float* cbuf   = (float*)carve((size_t)64 * 512 * 4);
    float* C_h    = (float*)carve((size_t)64 * 4608 * 4);
    float* mean_e = (float*)carve((size_t)64 * ENC * 4);
    float* h0f    = (float*)carve((size_t)64 * 512 * 4);
    __hip_bfloat16* hbuf   = (__hip_bfloat16*)carve((size_t)64 * 512 * 2);
    __hip_bfloat16* awebuf = (__hip_bfloat16*)carve((size_t)64 * 2048 * 2);
    __hip_bfloat16* hstore = (__hip_bfloat16*)carve((size_t)TSTEPS * 64 * 512 * 2);
    __hip_bfloat16* enc_s  = (__hip_bfloat16*)carve((size_t)64 * PDIM * ENC * 2);
    __hip_bfloat16* att1   = (__hip_bfloat16*)carve((size_t)64 * PDIM * 512 * 2);
    __hip_bfloat16* Wb_enc = (__hip_bfloat16*)carve((size_t)512 * 2048 * 2);
    __hip_bfloat16* Wb_bet = (__hip_bfloat16*)carve((size_t)2048 * 512 * 2);
    __hip_bfloat16* Wb_dec = (__hip_bfloat16*)carve((size_t)512 * 512 * 2);
    __hip_bfloat16* Wb_ih  = (__hip_bfloat16*)carve((size_t)2048 * 2560 * 2);
    __hip_bfloat16* Wb_hh  = (__hip_bfloat16*)carve((size_t)2048 * 512 * 2);
    __hip_bfloat16* Wb_fc  = (__hip_bfloat16*)carve((size_t)VOC * 512 * 2);
    // embs_all aliases Wb_enc (read-only after att1_gemm; written post-att1).
    __hip_bfloat16* embs_all = Wb_enc;   // 1.81MB <= 2MB

    // ---- init phase ----
    sort_kernel<<<1, 64, 0, stream>>>(clen, caps, sort_ind, dec_lens, caps_s,
                                      out_caps, out_dlen, out_sind);
    conv_enc_kernel<<<dim3(8, 64), 256, 0, stream>>>(enc, sort_ind, enc_s, mean_e);
    f2b_kernel<<<(512 * 2048 + 255) / 256, 256, 0, stream>>>(W_enc, Wb_enc, 512 * 2048);
    f2b_kernel<<<(2048 * 512 + 255) / 256, 256, 0, stream>>>(W_beta, Wb_bet, 2048 * 512);
    f2b_kernel<<<(512 * 512 + 255) / 256, 256, 0, stream>>>(W_dec, Wb_dec, 512 * 512);
    f2b_kernel<<<(2048 * 2560 + 255) / 256, 256, 0, stream>>>(W_ih, Wb_ih, 2048 * 2560);
    f2b_kernel<<<(2048 * 512 + 255) / 256, 256, 0, stream>>>(W_hh, Wb_hh, 2048 * 512);
    f2b_kernel<<<(VOC * 512 + 255) / 256, 256, 0, stream>>>(W_fc, Wb_fc, VOC * 512);

    gemm32_k<<<dim3(8, 1), 256, 0, stream>>>(mean_e, ENC, W_init_h, b_init_h, h0f, 512, ENC);
    gemm32_k<<<dim3(8, 1), 256, 0, stream>>>(mean_e, ENC, W_init_c, b_init_c, cbuf, 512, ENC);
    h0b_kernel<<<128, 256, 0, stream>>>(h0f, hbuf);

    // att1 (M=12544, N=512, K=2048) -> bf16 (last reader of Wb_enc)
    att1_gemm<<<dim3(196, 8), 64, 0, stream>>>(enc_s, Wb_enc, b_enc, att1);

    // embs_all (aliases Wb_enc; safe after att1_gemm)
    embgather_kernel<<<dim3(64, TSTEPS), 256, 0, stream>>>(emb_tab, caps_s, embs_all);

    // ---- decode: cooperative fast path, regular-launch fallback ----
    void* kargs[] = {
        (void*)&att1, (void*)&enc_s, (void*)&embs_all,
        (void*)&Wb_bet, (void*)&Wb_dec, (void*)&Wb_hh, (void*)&Wb_ih,
        (void*)&b_dec, (void*)&b_beta, (void*)&b_full, (void*)&w_full,
        (void*)&b_ih, (void*)&b_hh, (void*)&dec_lens,
        (void*)&hbuf, (void*)&cbuf, (void*)&C_h, (void*)&awebuf,
        (void*)&hstore, (void*)&out_alph };
    hipError_t cerr = hipLaunchCooperativeKernel((void*)decode_kernel, dim3(256),
                                                 dim3(256), kargs, 0, stream);
    if (cerr != hipSuccess) {
        (void)hipGetLastError();  // clear sticky error, use fallback path
        for (int t = 0; t < TSTEPS; ++t) {
            p1_kernel<<<72, 256, 0, stream>>>(hbuf, Wb_bet, Wb_dec, Wb_hh, C_h);
            p2_kernel<<<256, 256, 0, stream>>>(att1, enc_s, C_h, w_full, b_full,
                                               b_dec, b_beta, dec_lens, awebuf,
                                               out_alph, t);
            p3_kernel<<<32, 256, 0, stream>>>(awebuf, embs_all, Wb_ih, C_h,
                                              b_ih, b_hh, cbuf, hbuf, hstore, t);
        }
    }

    // batched preds over all timesteps (M=1856, N=10000, K=512)
    predsb_gemm<<<dim3(160, 58), 64, 0, stream>>>(hstore, Wb_fc, b_fc, dec_lens, out_pred);
}

// Round 8
// 3638.617 us; speedup vs baseline: 2.0203x; 2.0203x over previous
//
#include <hip/hip_runtime.h>
#include <hip/hip_bf16.h>
#include <math.h>
#include <float.h>

// Problem dims
#define BDIM   64
#define PDIM   196
#define ENC    2048
#define DECD   512
#define ATTD   512
#define EMBD   512
#define VOC    10000
#define LCAP   30
#define TSTEPS 29

typedef __attribute__((ext_vector_type(8))) short s8v;   // 8 x bf16
typedef __attribute__((ext_vector_type(4))) float f4v;   // MFMA acc

__device__ __forceinline__ float sigf(float x) { return 1.0f / (1.0f + expf(-x)); }
__device__ __forceinline__ float bf2f(ushort u) { return __uint_as_float(((uint)u) << 16); }

// ---------------------------------------------------------------------------
// Pipelined MFMA K-segment: NIT iterations of k+=32, 3-slot rotation.
// ---------------------------------------------------------------------------
template <int MF, int NF, int NIT>
__device__ __forceinline__ void gemm_seg(const __hip_bfloat16* const* arow,
                                         const __hip_bfloat16* const* wrow,
                                         f4v acc[][NF]) {
    s8v aP[3][MF], bP[3][NF];
    auto LD = [&](int it, int slot) {
#pragma unroll
        for (int mi = 0; mi < MF; ++mi) aP[slot][mi] = *(const s8v*)(arow[mi] + it * 32);
#pragma unroll
        for (int ni = 0; ni < NF; ++ni) bP[slot][ni] = *(const s8v*)(wrow[ni] + it * 32);
    };
    LD(0, 0);
    if constexpr (NIT > 1) LD(1, 1);
#pragma unroll
    for (int it = 0; it < NIT; ++it) {
        if (it + 2 < NIT) LD(it + 2, (it + 2) % 3);
        const int s = it % 3;
#pragma unroll
        for (int mi = 0; mi < MF; ++mi)
#pragma unroll
            for (int ni = 0; ni < NF; ++ni)
                acc[mi][ni] = __builtin_amdgcn_mfma_f32_16x16x32_bf16(aP[s][mi], bP[s][ni], acc[mi][ni], 0, 0, 0);
    }
}

// ===========================================================================
// Decode phases (HW-verified logic from r7's cooperative run)
// ===========================================================================

// P1: C_h[64][4608] = h @ [W_beta(2048)|W_dec(512)|W_hh(2048)]^T  (K=512)
// bid in [0,72): n-tile. wave w = m-tile (16 rows).
__device__ __forceinline__ void phase1(int bid, int tid,
    const __hip_bfloat16* hbuf, const __hip_bfloat16* Wb_bet,
    const __hip_bfloat16* Wb_dec, const __hip_bfloat16* Wb_hh, float* C_h) {
    const int l = tid & 63, c16 = l & 15, kg = l >> 4, w = tid >> 6;
    const int n0 = bid * 64;
    f4v acc[1][4];
#pragma unroll
    for (int ni = 0; ni < 4; ++ni) acc[0][ni] = (f4v)0.0f;
    const __hip_bfloat16* arow[1] = { hbuf + (size_t)(w * 16 + c16) * 512 + kg * 8 };
    const __hip_bfloat16* wrow[4];
#pragma unroll
    for (int ni = 0; ni < 4; ++ni) {
        int n = n0 + ni * 16 + c16;
        const __hip_bfloat16* wr;
        if (n < 2048)      wr = Wb_bet + (size_t)n * 512;
        else if (n < 2560) wr = Wb_dec + (size_t)(n - 2048) * 512;
        else               wr = Wb_hh + (size_t)(n - 2560) * 512;
        wrow[ni] = wr + kg * 8;
    }
    gemm_seg<1, 4, 16>(arow, wrow, acc);
#pragma unroll
    for (int ni = 0; ni < 4; ++ni)
#pragma unroll
        for (int i = 0; i < 4; ++i)
            C_h[(size_t)(w * 16 + kg * 4 + i) * 4608 + n0 + ni * 16 + c16] = acc[0][ni][i];
}

// P2: b = bid&63, q = bid>>6 (XCD swizzle: same-b blocks -> same XCD).
// e-scores + softmax (redundant per q), gated awe over cols [q*512,(q+1)*512).
__device__ __forceinline__ void phase2(int bid, int tid, float* smem,
    const __hip_bfloat16* att1, const __hip_bfloat16* enc_s, const float* C_h,
    const float* w_full, const float* b_full, const float* b_dec,
    const float* b_beta, const int* dec_lens,
    __hip_bfloat16* awebuf, float* out_alphas, int t) {
    const int b = bid & 63, q = bid >> 6;
    const int l = tid & 63, w = tid >> 6;
    float* s_att2 = smem;            // [0,512)
    float* s_wf   = smem + 512;      // [512,1024)
    float* s_e    = smem + 1024;     // [1024,1280)
    float* red    = smem + 1280;     // [1280,1536)
    float* s_part = smem + 1536;     // [1536,3584)

    s_att2[tid]       = C_h[(size_t)b * 4608 + 2048 + tid]       + b_dec[tid];
    s_att2[tid + 256] = C_h[(size_t)b * 4608 + 2048 + 256 + tid] + b_dec[256 + tid];
    s_wf[tid]       = w_full[tid];
    s_wf[tid + 256] = w_full[tid + 256];
    __syncthreads();

    // e-scores (all q compute all 196 identically; wave w does p = w mod 4)
    const float bf = b_full[0];
    const int a0 = l << 3;
    for (int p = w; p < PDIM; p += 4) {
        const ushort* row = (const ushort*)att1 + ((size_t)b * PDIM + p) * 512 + a0;
        s8v u = *(const s8v*)row;
        float s = 0.f;
#pragma unroll
        for (int i = 0; i < 8; ++i) {
            float x = bf2f((ushort)u[i]) + s_att2[a0 + i];
            s += fmaxf(x, 0.f) * s_wf[a0 + i];
        }
#pragma unroll
        for (int off = 32; off; off >>= 1) s += __shfl_xor(s, off);
        if (l == 0) s_e[p] = s + bf;
    }
    __syncthreads();

    // softmax over 196 (alpha stays in s_e)
    float v = (tid < PDIM) ? s_e[tid] : -FLT_MAX;
    red[tid] = v;
    __syncthreads();
    for (int st = 128; st; st >>= 1) {
        if (tid < st) red[tid] = fmaxf(red[tid], red[tid + st]);
        __syncthreads();
    }
    float mx = red[0];
    __syncthreads();
    float ex = (tid < PDIM) ? expf(v - mx) : 0.f;
    red[tid] = ex;
    __syncthreads();
    for (int st = 128; st; st >>= 1) {
        if (tid < st) red[tid] += red[tid + st];
        __syncthreads();
    }
    float inv = 1.f / red[0];
    __syncthreads();
    if (tid < PDIM) {
        float al = ex * inv;
        s_e[tid] = al;
        if (q == 0)
            out_alphas[(size_t)b * (TSTEPS * PDIM) + (size_t)t * PDIM + tid] =
                (t < dec_lens[b]) ? al : 0.f;
    }
    __syncthreads();

    // awe: wave w sums its 49 p-rows over this block's 512-col slice
    const int c0 = q * 512 + l * 8;
    const ushort* ep = (const ushort*)enc_s + (size_t)b * (PDIM * ENC) + c0;
    float a8[8];
#pragma unroll
    for (int i = 0; i < 8; ++i) a8[i] = 0.f;
    for (int p = w * 49; p < w * 49 + 49; ++p) {
        float al = s_e[p];
        s8v u = *(const s8v*)(ep + (size_t)p * ENC);
#pragma unroll
        for (int i = 0; i < 8; ++i) a8[i] += al * bf2f((ushort)u[i]);
    }
#pragma unroll
    for (int i = 0; i < 8; ++i) s_part[w * 512 + l * 8 + i] = a8[i];
    __syncthreads();
#pragma unroll
    for (int u2 = 0; u2 < 2; ++u2) {
        int cc = tid * 2 + u2;
        float s = s_part[cc] + s_part[512 + cc] + s_part[1024 + cc] + s_part[1536 + cc];
        int gcol = q * 512 + cc;
        float gate = sigf(C_h[(size_t)b * 4608 + gcol] + b_beta[gcol]);
        awebuf[(size_t)b * 2048 + gcol] = __float2bfloat16(s * gate);
    }
}

// P3: gates = emb@W_ihE^T + awe@W_ihA^T + C_h(hh) + biases -> LSTM cell.
// bid in [0,32): j-slice of 16. Wave w = gate w (full K per wave).
__device__ __forceinline__ void phase3(int bid, int tid, float* smem,
    const __hip_bfloat16* awebuf, const __hip_bfloat16* embs_all,
    const __hip_bfloat16* Wb_ih, const float* C_h,
    const float* b_ih, const float* b_hh,
    float* cbuf, __hip_bfloat16* hbuf, __hip_bfloat16* hstore, int t) {
    const int l = tid & 63, c16 = l & 15, kg = l >> 4, w = tid >> 6;
    const int j0 = bid * 16;
    f4v acc[4][1];
#pragma unroll
    for (int mi = 0; mi < 4; ++mi) acc[mi][0] = (f4v)0.0f;
    const __hip_bfloat16* arow[4];
    const __hip_bfloat16* wrow[1];
    const __hip_bfloat16* wbase = Wb_ih + (size_t)(512 * w + j0 + c16) * 2560;
    // emb segment: W_ih cols [0,512)
#pragma unroll
    for (int mi = 0; mi < 4; ++mi)
        arow[mi] = embs_all + ((size_t)t * 64 + mi * 16 + c16) * 512 + kg * 8;
    wrow[0] = wbase + kg * 8;
    gemm_seg<4, 1, 16>(arow, wrow, acc);
    // awe segment: W_ih cols [512,2560)
#pragma unroll
    for (int mi = 0; mi < 4; ++mi)
        arow[mi] = awebuf + (size_t)(mi * 16 + c16) * 2048 + kg * 8;
    wrow[0] = wbase + 512 + kg * 8;
    gemm_seg<4, 1, 64>(arow, wrow, acc);
    // dump: smem[gate w][64 rows][16 cols]
#pragma unroll
    for (int mi = 0; mi < 4; ++mi)
#pragma unroll
        for (int i = 0; i < 4; ++i)
            smem[w * 1024 + (mi * 16 + kg * 4 + i) * 16 + c16] = acc[mi][0][i];
    __syncthreads();
    // cell: 1024 (b,jj) pairs over 4 iterations
#pragma unroll
    for (int u2 = 0; u2 < 4; ++u2) {
        int pid = u2 * 256 + tid;
        int b = pid >> 4, jj = pid & 15;
        float vg[4];
#pragma unroll
        for (int g = 0; g < 4; ++g) {
            int col = 512 * g + j0 + jj;
            vg[g] = smem[g * 1024 + b * 16 + jj]
                  + C_h[(size_t)b * 4608 + 2560 + col]
                  + b_ih[col] + b_hh[col];
        }
        float i_ = sigf(vg[0]), f_ = sigf(vg[1]), gg = tanhf(vg[2]), o_ = sigf(vg[3]);
        int cidx = b * 512 + j0 + jj;
        float cn = f_ * cbuf[cidx] + i_ * gg;
        cbuf[cidx] = cn;
        __hip_bfloat16 hb = __float2bfloat16(o_ * tanhf(cn));
        hbuf[cidx] = hb;
        hstore[(size_t)t * (64 * 512) + cidx] = hb;
    }
}

// Per-phase kernels (regular launches; no grid.sync)
__global__ __launch_bounds__(256) void p1_kernel(
    const __hip_bfloat16* hbuf, const __hip_bfloat16* Wb_bet,
    const __hip_bfloat16* Wb_dec, const __hip_bfloat16* Wb_hh, float* C_h) {
    phase1(blockIdx.x, threadIdx.x, hbuf, Wb_bet, Wb_dec, Wb_hh, C_h);
}
__global__ __launch_bounds__(256) void p2_kernel(
    const __hip_bfloat16* att1, const __hip_bfloat16* enc_s, const float* C_h,
    const float* w_full, const float* b_full, const float* b_dec,
    const float* b_beta, const int* dec_lens,
    __hip_bfloat16* awebuf, float* out_alphas, int t) {
    __shared__ float smem[4096];
    phase2(blockIdx.x, threadIdx.x, smem, att1, enc_s, C_h, w_full, b_full,
           b_dec, b_beta, dec_lens, awebuf, out_alphas, t);
}
__global__ __launch_bounds__(256) void p3_kernel(
    const __hip_bfloat16* awebuf, const __hip_bfloat16* embs_all,
    const __hip_bfloat16* Wb_ih, const float* C_h,
    const float* b_ih, const float* b_hh,
    float* cbuf, __hip_bfloat16* hbuf, __hip_bfloat16* hstore, int t) {
    __shared__ float smem[4096];
    phase3(blockIdx.x, threadIdx.x, smem, awebuf, embs_all, Wb_ih, C_h,
           b_ih, b_hh, cbuf, hbuf, hstore, t);
}

// ===========================================================================
// Init-phase kernels
// ===========================================================================
__global__ void sort_kernel(const int* __restrict__ cap_len,
                            const int* __restrict__ caps,
                            int* __restrict__ sort_ind,
                            int* __restrict__ dec_lens,
                            int* __restrict__ caps_s,
                            float* __restrict__ out_caps,
                            float* __restrict__ out_dlen,
                            float* __restrict__ out_sind) {
    int i = threadIdx.x;  // 64 threads
    __shared__ int len[BDIM];
    len[i] = cap_len[i];
    __syncthreads();
    int li = len[i];
    int r = 0;
    for (int j = 0; j < BDIM; ++j) {
        int lj = len[j];
        if (lj > li || (lj == li && j < i)) ++r;
    }
    sort_ind[r] = i;
    dec_lens[r] = li - 1;
    out_sind[r] = (float)i;
    out_dlen[r] = (float)(li - 1);
    for (int tt = 0; tt < LCAP; ++tt) {
        int v = caps[i * LCAP + tt];
        caps_s[r * LCAP + tt] = v;
        out_caps[r * LCAP + tt] = (float)v;
    }
}

__global__ __launch_bounds__(256) void conv_enc_kernel(const float* __restrict__ enc,
                                                       const int* __restrict__ sort_ind,
                                                       __hip_bfloat16* __restrict__ enc_s,
                                                       float* __restrict__ mean_enc) {
    int b = blockIdx.y, tid = threadIdx.x;
    int e = (blockIdx.x << 8) + tid;
    const float* ep = enc + (size_t)sort_ind[b] * (PDIM * ENC) + e;
    __hip_bfloat16* op = enc_s + (size_t)b * (PDIM * ENC) + e;
    float s = 0.f;
    for (int p = 0; p < PDIM; ++p) {
        float v = ep[(size_t)p * ENC];
        s += v;
        op[(size_t)p * ENC] = __float2bfloat16(v);
    }
    mean_enc[(size_t)b * ENC + e] = s * (1.0f / (float)PDIM);
}

__global__ __launch_bounds__(256) void f2b_kernel(const float* __restrict__ src,
                                                  __hip_bfloat16* __restrict__ dst, int n) {
    int i = blockIdx.x * 256 + threadIdx.x;
    if (i < n) dst[i] = __float2bfloat16(src[i]);
}

__global__ __launch_bounds__(256) void h0b_kernel(const float* __restrict__ h0f,
                                                  __hip_bfloat16* __restrict__ hbuf) {
    int idx = blockIdx.x * 256 + threadIdx.x;  // < 64*512
    hbuf[idx] = __float2bfloat16(h0f[idx]);
}

__global__ __launch_bounds__(256) void embgather_kernel(
    const float* __restrict__ emb_table, const int* __restrict__ caps_s,
    __hip_bfloat16* __restrict__ embs_all) {
    int b = blockIdx.x, t = blockIdx.y;
    int cap = caps_s[b * LCAP + t];
    int j = threadIdx.x << 1;
    float2 e = *(const float2*)(emb_table + (size_t)cap * EMBD + j);
    __hip_bfloat16 eb[2];
    eb[0] = __float2bfloat16(e.x); eb[1] = __float2bfloat16(e.y);
    *(uint*)(embs_all + ((size_t)t * 64 + b) * 512 + j) = *(uint*)eb;
}

__global__ __launch_bounds__(256) void gemm32_k(
    const float* __restrict__ A, int lda,
    const float* __restrict__ W0, const float* __restrict__ bias0,
    float* __restrict__ C, int ldc, int K) {
    __shared__ float As[16][64];
    __shared__ float Ws[16][64];
    const int tid = threadIdx.x;
    const int tx = tid & 15, ty = tid >> 4;
    const int bn0 = blockIdx.x * 64;
    const int lr = tid >> 2;
    const int lk = (tid & 3) << 2;
    const float* Arow = A + (size_t)lr * lda;
    const int wn = bn0 + lr;
    float acc[4][4];
#pragma unroll
    for (int i = 0; i < 4; ++i)
#pragma unroll
        for (int j = 0; j < 4; ++j) acc[i][j] = 0.f;
    for (int k0 = 0; k0 < K; k0 += 16) {
        float4 av = *(const float4*)(Arow + k0 + lk);
        float4 wv = *(const float4*)(W0 + (size_t)wn * K + k0 + lk);
        __syncthreads();
        As[lk + 0][lr] = av.x; As[lk + 1][lr] = av.y;
        As[lk + 2][lr] = av.z; As[lk + 3][lr] = av.w;
        Ws[lk + 0][lr] = wv.x; Ws[lk + 1][lr] = wv.y;
        Ws[lk + 2][lr] = wv.z; Ws[lk + 3][lr] = wv.w;
        __syncthreads();
#pragma unroll
        for (int kk = 0; kk < 16; ++kk) {
            const float4 a = *(const float4*)&As[kk][ty << 2];
            const float4 w = *(const float4*)&Ws[kk][tx << 2];
            acc[0][0] += a.x * w.x; acc[0][1] += a.x * w.y; acc[0][2] += a.x * w.z; acc[0][3] += a.x * w.w;
            acc[1][0] += a.y * w.x; acc[1][1] += a.y * w.y; acc[1][2] += a.y * w.z; acc[1][3] += a.y * w.w;
            acc[2][0] += a.z * w.x; acc[2][1] += a.z * w.y; acc[2][2] += a.z * w.z; acc[2][3] += a.z * w.w;
            acc[3][0] += a.w * w.x; acc[3][1] += a.w * w.y; acc[3][2] += a.w * w.z; acc[3][3] += a.w * w.w;
        }
    }
#pragma unroll
    for (int i = 0; i < 4; ++i) {
        int row = (ty << 2) + i;
#pragma unroll
        for (int j = 0; j < 4; ++j) {
            int col = bn0 + (tx << 2) + j;
            C[(size_t)row * ldc + col] = acc[i][j] + bias0[col];
        }
    }
}

// att1 = enc_s @ W_enc^T + b_enc -> bf16. 256 thr, wave w = m-subtile (16 rows),
// shared n-tile (B-loads L1-shared). grid (196, 8): 6272 waves (~6/SIMD).
__global__ __launch_bounds__(256) void att1_gemm(
    const __hip_bfloat16* __restrict__ A, const __hip_bfloat16* __restrict__ W,
    const float* __restrict__ bias, __hip_bfloat16* __restrict__ C) {
    const int tid = threadIdx.x;
    const int l = tid & 63, c16 = l & 15, kg = l >> 4, w = tid >> 6;
    const int m0 = blockIdx.x * 64 + w * 16, n0 = blockIdx.y * 64;
    f4v acc[1][4];
#pragma unroll
    for (int ni = 0; ni < 4; ++ni) acc[0][ni] = (f4v)0.0f;
    const __hip_bfloat16* arow[1] = { A + (size_t)(m0 + c16) * ENC + kg * 8 };
    const __hip_bfloat16* wrow[4];
#pragma unroll
    for (int ni = 0; ni < 4; ++ni)
        wrow[ni] = W + (size_t)(n0 + ni * 16 + c16) * ENC + kg * 8;
    gemm_seg<1, 4, 64>(arow, wrow, acc);
#pragma unroll
    for (int ni = 0; ni < 4; ++ni)
#pragma unroll
        for (int i = 0; i < 4; ++i) {
            int r = m0 + kg * 4 + i;
            int c = n0 + ni * 16 + c16;
            C[(size_t)r * 512 + c] = __float2bfloat16(acc[0][ni][i] + bias[c]);
        }
}

__global__ __launch_bounds__(64) void predsb_gemm(
    const __hip_bfloat16* __restrict__ Hs,   // [1856][512]
    const __hip_bfloat16* __restrict__ Wfc,  // [10000][512]
    const float* __restrict__ bias,
    const int* __restrict__ dec_lens,
    float* __restrict__ out) {
    const int l = threadIdx.x, c16 = l & 15, kg = l >> 4;
    const int n0 = blockIdx.x * 64, m0 = blockIdx.y * 32;
    f4v acc[2][4];
#pragma unroll
    for (int mi = 0; mi < 2; ++mi)
#pragma unroll
        for (int ni = 0; ni < 4; ++ni) acc[mi][ni] = (f4v)0.0f;
    const __hip_bfloat16* arow[2];
#pragma unroll
    for (int mi = 0; mi < 2; ++mi)
        arow[mi] = Hs + (size_t)(m0 + mi * 16 + c16) * 512 + kg * 8;
    const __hip_bfloat16* wrow[4];
#pragma unroll
    for (int ni = 0; ni < 4; ++ni) {
        int n = n0 + ni * 16 + c16;
        int nn = (n < VOC) ? n : (VOC - 1);
        wrow[ni] = Wfc + (size_t)nn * 512 + kg * 8;
    }
    gemm_seg<2, 4, 16>(arow, wrow, acc);
#pragma unroll
    for (int mi = 0; mi < 2; ++mi)
#pragma unroll
        for (int ni = 0; ni < 4; ++ni)
#pragma unroll
            for (int i = 0; i < 4; ++i) {
                int r = m0 + mi * 16 + kg * 4 + i;
                int c = n0 + ni * 16 + c16;
                if (c < VOC) {
                    int tt = r >> 6, b = r & 63;
                    float v = acc[mi][ni][i] + bias[c];
                    out[(size_t)b * (TSTEPS * VOC) + (size_t)tt * VOC + c] =
                        (tt < dec_lens[b]) ? v : 0.f;
                }
            }
}

// ---------------------------------------------------------------------------
extern "C" void kernel_launch(void* const* d_in, const int* in_sizes, int n_in,
                              void* d_out, int out_size, void* d_ws, size_t ws_size,
                              hipStream_t stream) {
    const float* enc      = (const float*)d_in[0];
    const int*   caps     = (const int*)d_in[1];
    const int*   clen     = (const int*)d_in[2];
    const float* W_enc    = (const float*)d_in[3];
    const float* b_enc    = (const float*)d_in[4];
    const float* W_dec    = (const float*)d_in[5];
    const float* b_dec    = (const float*)d_in[6];
    const float* w_full   = (const float*)d_in[7];
    const float* b_full   = (const float*)d_in[8];
    const float* emb_tab  = (const float*)d_in[9];
    const float* W_ih     = (const float*)d_in[10];
    const float* b_ih     = (const float*)d_in[11];
    const float* W_hh     = (const float*)d_in[12];
    const float* b_hh     = (const float*)d_in[13];
    const float* W_init_h = (const float*)d_in[14];
    const float* b_init_h = (const float*)d_in[15];
    const float* W_init_c = (const float*)d_in[16];
    const float* b_init_c = (const float*)d_in[17];
    const float* W_beta   = (const float*)d_in[18];
    const float* b_beta   = (const float*)d_in[19];
    const float* W_fc     = (const float*)d_in[20];
    const float* b_fc     = (const float*)d_in[21];

    float* out_pred = (float*)d_out;
    float* out_alph = out_pred + (size_t)BDIM * TSTEPS * VOC;
    float* out_caps = out_alph + (size_t)BDIM * TSTEPS * PDIM;
    float* out_dlen = out_caps + BDIM * LCAP;
    float* out_sind = out_dlen + BDIM;

    // ---- workspace carve-up (256B aligned) ----
    char* p = (char*)d_ws;
    auto carve = [&](size_t bytes) { char* r = p; p += (bytes + 255) & ~(size_t)255; return r; };
    int* sort_ind = (int*)carve(64 * 4);
    int* dec_lens = (int*)carve(64 * 4);
    int* caps_s   = (int*)carve(64 * LCAP * 4);
    float* cbuf   = (float*)carve((size_t)64 * 512 * 4);
    float* C_h    = (float*)carve((size_t)64 * 4608 * 4);
    float* mean_e = (float*)carve((size_t)64 * ENC * 4);
    float* h0f    = (float*)carve((size_t)64 * 512 * 4);
    __hip_bfloat16* hbuf   = (__hip_bfloat16*)carve((size_t)64 * 512 * 2);
    __hip_bfloat16* awebuf = (__hip_bfloat16*)carve((size_t)64 * 2048 * 2);
    __hip_bfloat16* hstore = (__hip_bfloat16*)carve((size_t)TSTEPS * 64 * 512 * 2);
    __hip_bfloat16* enc_s  = (__hip_bfloat16*)carve((size_t)64 * PDIM * ENC * 2);
    __hip_bfloat16* att1   = (__hip_bfloat16*)carve((size_t)64 * PDIM * 512 * 2);
    __hip_bfloat16* Wb_enc = (__hip_bfloat16*)carve((size_t)512 * 2048 * 2);
    __hip_bfloat16* Wb_bet = (__hip_bfloat16*)carve((size_t)2048 * 512 * 2);
    __hip_bfloat16* Wb_dec = (__hip_bfloat16*)carve((size_t)512 * 512 * 2);
    __hip_bfloat16* Wb_ih  = (__hip_bfloat16*)carve((size_t)2048 * 2560 * 2);
    __hip_bfloat16* Wb_hh  = (__hip_bfloat16*)carve((size_t)2048 * 512 * 2);
    __hip_bfloat16* Wb_fc  = (__hip_bfloat16*)carve((size_t)VOC * 512 * 2);
    // embs_all aliases Wb_enc (written after att1_gemm's last read of Wb_enc)
    __hip_bfloat16* embs_all = Wb_enc;   // 1.81MB <= 2MB

    // ---- init phase ----
    sort_kernel<<<1, 64, 0, stream>>>(clen, caps, sort_ind, dec_lens, caps_s,
                                      out_caps, out_dlen, out_sind);
    conv_enc_kernel<<<dim3(8, 64), 256, 0, stream>>>(enc, sort_ind, enc_s, mean_e);
    f2b_kernel<<<(512 * 2048 + 255) / 256, 256, 0, stream>>>(W_enc, Wb_enc, 512 * 2048);
    f2b_kernel<<<(2048 * 512 + 255) / 256, 256, 0, stream>>>(W_beta, Wb_bet, 2048 * 512);
    f2b_kernel<<<(512 * 512 + 255) / 256, 256, 0, stream>>>(W_dec, Wb_dec, 512 * 512);
    f2b_kernel<<<(2048 * 2560 + 255) / 256, 256, 0, stream>>>(W_ih, Wb_ih, 2048 * 2560);
    f2b_kernel<<<(2048 * 512 + 255) / 256, 256, 0, stream>>>(W_hh, Wb_hh, 2048 * 512);
    f2b_kernel<<<(VOC * 512 + 255) / 256, 256, 0, stream>>>(W_fc, Wb_fc, VOC * 512);

    gemm32_k<<<dim3(8, 1), 256, 0, stream>>>(mean_e, ENC, W_init_h, b_init_h, h0f, 512, ENC);
    gemm32_k<<<dim3(8, 1), 256, 0, stream>>>(mean_e, ENC, W_init_c, b_init_c, cbuf, 512, ENC);
    h0b_kernel<<<128, 256, 0, stream>>>(h0f, hbuf);

    // att1 (M=12544, N=512, K=2048) -> bf16 (last reader of Wb_enc)
    att1_gemm<<<dim3(196, 8), 256, 0, stream>>>(enc_s, Wb_enc, b_enc, att1);

    // embs_all (aliases Wb_enc; safe after att1_gemm)
    embgather_kernel<<<dim3(64, TSTEPS), 256, 0, stream>>>(emb_tab, caps_s, embs_all);

    // ---- decode loop: 3 regular launches per step ----
    for (int t = 0; t < TSTEPS; ++t) {
        p1_kernel<<<72, 256, 0, stream>>>(hbuf, Wb_bet, Wb_dec, Wb_hh, C_h);
        p2_kernel<<<256, 256, 0, stream>>>(att1, enc_s, C_h, w_full, b_full,
                                           b_dec, b_beta, dec_lens, awebuf,
                                           out_alph, t);
        p3_kernel<<<32, 256, 0, stream>>>(awebuf, embs_all, Wb_ih, C_h,
                                          b_ih, b_hh, cbuf, hbuf, hstore, t);
    }

    // batched preds over all timesteps (M=1856, N=10000, K=512)
    predsb_gemm<<<dim3(160, 58), 64, 0, stream>>>(hstore, Wb_fc, b_fc, dec_lens, out_pred);
}

// Round 10
// 3286.017 us; speedup vs baseline: 2.2371x; 1.1073x over previous
//
#include <hip/hip_runtime.h>
#include <hip/hip_bf16.h>
#include <math.h>
#include <float.h>

// Problem dims
#define BDIM   64
#define PDIM   196
#define ENC    2048
#define DECD   512
#define ATTD   512
#define EMBD   512
#define VOC    10000
#define LCAP   30
#define TSTEPS 29

typedef __attribute__((ext_vector_type(8))) short s8v;   // 8 x bf16
typedef __attribute__((ext_vector_type(4))) float f4v;   // MFMA acc

__device__ __forceinline__ float sigf(float x) { return 1.0f / (1.0f + expf(-x)); }
__device__ __forceinline__ float bf2f(ushort u) { return __uint_as_float(((uint)u) << 16); }

// ---------------------------------------------------------------------------
// Pipelined MFMA K-segment: NIT iterations of k+=32, 3-slot rotation.
// ---------------------------------------------------------------------------
template <int MF, int NF, int NIT>
__device__ __forceinline__ void gemm_seg(const __hip_bfloat16* const* arow,
                                         const __hip_bfloat16* const* wrow,
                                         f4v acc[][NF]) {
    s8v aP[3][MF], bP[3][NF];
    auto LD = [&](int it, int slot) {
#pragma unroll
        for (int mi = 0; mi < MF; ++mi) aP[slot][mi] = *(const s8v*)(arow[mi] + it * 32);
#pragma unroll
        for (int ni = 0; ni < NF; ++ni) bP[slot][ni] = *(const s8v*)(wrow[ni] + it * 32);
    };
    LD(0, 0);
    if constexpr (NIT > 1) LD(1, 1);
#pragma unroll
    for (int it = 0; it < NIT; ++it) {
        if (it + 2 < NIT) LD(it + 2, (it + 2) % 3);
        const int s = it % 3;
#pragma unroll
        for (int mi = 0; mi < MF; ++mi)
#pragma unroll
            for (int ni = 0; ni < NF; ++ni)
                acc[mi][ni] = __builtin_amdgcn_mfma_f32_16x16x32_bf16(aP[s][mi], bP[s][ni], acc[mi][ni], 0, 0, 0);
    }
}

// ===========================================================================
// Decode phases
// ===========================================================================

// P1: C_h[64][4608] = h @ [W_beta(2048)|W_dec(512)|W_hh(2048)]^T  (K=512)
__device__ __forceinline__ void phase1(int bid, int tid,
    const __hip_bfloat16* hbuf, const __hip_bfloat16* Wb_bet,
    const __hip_bfloat16* Wb_dec, const __hip_bfloat16* Wb_hh, float* C_h) {
    const int l = tid & 63, c16 = l & 15, kg = l >> 4, w = tid >> 6;
    const int n0 = bid * 64;
    f4v acc[1][4];
#pragma unroll
    for (int ni = 0; ni < 4; ++ni) acc[0][ni] = (f4v)0.0f;
    const __hip_bfloat16* arow[1] = { hbuf + (size_t)(w * 16 + c16) * 512 + kg * 8 };
    const __hip_bfloat16* wrow[4];
#pragma unroll
    for (int ni = 0; ni < 4; ++ni) {
        int n = n0 + ni * 16 + c16;
        const __hip_bfloat16* wr;
        if (n < 2048)      wr = Wb_bet + (size_t)n * 512;
        else if (n < 2560) wr = Wb_dec + (size_t)(n - 2048) * 512;
        else               wr = Wb_hh + (size_t)(n - 2560) * 512;
        wrow[ni] = wr + kg * 8;
    }
    gemm_seg<1, 4, 16>(arow, wrow, acc);
#pragma unroll
    for (int ni = 0; ni < 4; ++ni)
#pragma unroll
        for (int i = 0; i < 4; ++i)
            C_h[(size_t)(w * 16 + kg * 4 + i) * 4608 + n0 + ni * 16 + c16] = acc[0][ni][i];
}

// P2: b = bid&63, q = bid>>6 (XCD: all 4 q-blocks of b on XCD b%8).
// e-scores + softmax (redundant per q), gated awe over cols [q*512,(q+1)*512).
// Load loops batched 8-deep (8 independent 16B loads in flight).
__device__ __forceinline__ void phase2(int bid, int tid, float* smem,
    const __hip_bfloat16* att1, const __hip_bfloat16* enc_s, const float* C_h,
    const float* w_full, const float* b_full, const float* b_dec,
    const float* b_beta, const int* dec_lens,
    __hip_bfloat16* awebuf, float* out_alphas, int t) {
    const int b = bid & 63, q = bid >> 6;
    const int l = tid & 63, w = tid >> 6;
    float* s_att2 = smem;            // [0,512)
    float* s_wf   = smem + 512;      // [512,1024)
    float* s_e    = smem + 1024;     // [1024,1280)
    float* red    = smem + 1280;     // [1280,1536)
    float* s_part = smem + 1536;     // [1536,3584)

    s_att2[tid]       = C_h[(size_t)b * 4608 + 2048 + tid]       + b_dec[tid];
    s_att2[tid + 256] = C_h[(size_t)b * 4608 + 2048 + 256 + tid] + b_dec[256 + tid];
    s_wf[tid]       = w_full[tid];
    s_wf[tid + 256] = w_full[tid + 256];
    __syncthreads();

    // e-scores: wave w owns rows [w*49, w*49+49); batches of 8.
    const float bf = b_full[0];
    const int a0 = l << 3;
    const int p0 = w * 49;
    const ushort* abase = (const ushort*)att1 + ((size_t)b * PDIM) * 512 + a0;
    {
        s8v u[8];
#pragma unroll 1
        for (int pb = 0; pb < 48; pb += 8) {
#pragma unroll
            for (int i = 0; i < 8; ++i)
                u[i] = *(const s8v*)(abase + (size_t)(p0 + pb + i) * 512);
#pragma unroll
            for (int i = 0; i < 8; ++i) {
                float s = 0.f;
#pragma unroll
                for (int j = 0; j < 8; ++j) {
                    float x = bf2f((ushort)u[i][j]) + s_att2[a0 + j];
                    s += fmaxf(x, 0.f) * s_wf[a0 + j];
                }
#pragma unroll
                for (int off = 32; off; off >>= 1) s += __shfl_xor(s, off);
                if (l == 0) s_e[p0 + pb + i] = s + bf;
            }
        }
        // tail p0+48
        s8v ut = *(const s8v*)(abase + (size_t)(p0 + 48) * 512);
        float s = 0.f;
#pragma unroll
        for (int j = 0; j < 8; ++j) {
            float x = bf2f((ushort)ut[j]) + s_att2[a0 + j];
            s += fmaxf(x, 0.f) * s_wf[a0 + j];
        }
#pragma unroll
        for (int off = 32; off; off >>= 1) s += __shfl_xor(s, off);
        if (l == 0) s_e[p0 + 48] = s + bf;
    }
    __syncthreads();

    // softmax over 196 (alpha stays in s_e)
    float v = (tid < PDIM) ? s_e[tid] : -FLT_MAX;
    red[tid] = v;
    __syncthreads();
    for (int st = 128; st; st >>= 1) {
        if (tid < st) red[tid] = fmaxf(red[tid], red[tid + st]);
        __syncthreads();
    }
    float mx = red[0];
    __syncthreads();
    float ex = (tid < PDIM) ? expf(v - mx) : 0.f;
    red[tid] = ex;
    __syncthreads();
    for (int st = 128; st; st >>= 1) {
        if (tid < st) red[tid] += red[tid + st];
        __syncthreads();
    }
    float inv = 1.f / red[0];
    __syncthreads();
    if (tid < PDIM) {
        float al = ex * inv;
        s_e[tid] = al;
        if (q == 0)
            out_alphas[(size_t)b * (TSTEPS * PDIM) + (size_t)t * PDIM + tid] =
                (t < dec_lens[b]) ? al : 0.f;
    }
    __syncthreads();

    // awe: wave w sums rows [w*49,w*49+49) over this block's 512-col slice;
    // batches of 8.
    const int c0 = q * 512 + l * 8;
    const ushort* ep = (const ushort*)enc_s + (size_t)b * (PDIM * ENC) + c0;
    float a8[8];
#pragma unroll
    for (int i = 0; i < 8; ++i) a8[i] = 0.f;
    {
        s8v u[8];
#pragma unroll 1
        for (int pb = 0; pb < 48; pb += 8) {
#pragma unroll
            for (int i = 0; i < 8; ++i)
                u[i] = *(const s8v*)(ep + (size_t)(p0 + pb + i) * ENC);
#pragma unroll
            for (int i = 0; i < 8; ++i) {
                float al = s_e[p0 + pb + i];
#pragma unroll
                for (int j = 0; j < 8; ++j) a8[j] += al * bf2f((ushort)u[i][j]);
            }
        }
        s8v ut = *(const s8v*)(ep + (size_t)(p0 + 48) * ENC);
        float al = s_e[p0 + 48];
#pragma unroll
        for (int j = 0; j < 8; ++j) a8[j] += al * bf2f((ushort)ut[j]);
    }
#pragma unroll
    for (int i = 0; i < 8; ++i) s_part[w * 512 + l * 8 + i] = a8[i];
    __syncthreads();
#pragma unroll
    for (int u2 = 0; u2 < 2; ++u2) {
        int cc = tid * 2 + u2;
        float s = s_part[cc] + s_part[512 + cc] + s_part[1024 + cc] + s_part[1536 + cc];
        int gcol = q * 512 + cc;
        float gate = sigf(C_h[(size_t)b * 4608 + gcol] + b_beta[gcol]);
        awebuf[(size_t)b * 2048 + gcol] = __float2bfloat16(s * gate);
    }
}

// P3: gates = emb@W_ihE^T + awe@W_ihA^T + C_h(hh) + biases -> LSTM cell.
// 512 threads: wave w = (kh = w>>2, gate g = w&3); K split in halves (chain 40).
__device__ __forceinline__ void phase3(int bid, int tid, float* smem,
    const __hip_bfloat16* awebuf, const __hip_bfloat16* embs_all,
    const __hip_bfloat16* Wb_ih, const float* C_h,
    const float* b_ih, const float* b_hh,
    float* cbuf, __hip_bfloat16* hbuf, __hip_bfloat16* hstore, int t) {
    const int l = tid & 63, c16 = l & 15, kg = l >> 4, w = tid >> 6;
    const int g = w & 3, kh = w >> 2;
    const int j0 = bid * 16;
    f4v acc[4][1];
#pragma unroll
    for (int mi = 0; mi < 4; ++mi) acc[mi][0] = (f4v)0.0f;
    const __hip_bfloat16* arow[4];
    const __hip_bfloat16* wrow[1];
    const __hip_bfloat16* wbase = Wb_ih + (size_t)(512 * g + j0 + c16) * 2560;
    if (kh == 0) {
        // emb segment: W_ih cols [0,512)
#pragma unroll
        for (int mi = 0; mi < 4; ++mi)
            arow[mi] = embs_all + ((size_t)t * 64 + mi * 16 + c16) * 512 + kg * 8;
        wrow[0] = wbase + kg * 8;
        gemm_seg<4, 1, 16>(arow, wrow, acc);
        // awe k [0,768) : W_ih cols [512,1280)
#pragma unroll
        for (int mi = 0; mi < 4; ++mi)
            arow[mi] = awebuf + (size_t)(mi * 16 + c16) * 2048 + kg * 8;
        wrow[0] = wbase + 512 + kg * 8;
        gemm_seg<4, 1, 24>(arow, wrow, acc);
    } else {
        // awe k [768,2048) : W_ih cols [1280,2560)
#pragma unroll
        for (int mi = 0; mi < 4; ++mi)
            arow[mi] = awebuf + (size_t)(mi * 16 + c16) * 2048 + 768 + kg * 8;
        wrow[0] = wbase + 1280 + kg * 8;
        gemm_seg<4, 1, 40>(arow, wrow, acc);
    }
    // dump: smem[w][64 rows][16 cols]
#pragma unroll
    for (int mi = 0; mi < 4; ++mi)
#pragma unroll
        for (int i = 0; i < 4; ++i)
            smem[w * 1024 + (mi * 16 + kg * 4 + i) * 16 + c16] = acc[mi][0][i];
    __syncthreads();
    // cell: 1024 (b,jj) pairs over 2 iterations (512 threads)
#pragma unroll
    for (int u2 = 0; u2 < 2; ++u2) {
        int pid = u2 * 512 + tid;
        int b = pid >> 4, jj = pid & 15;
        int idx = b * 16 + jj;
        float vg[4];
#pragma unroll
        for (int gg2 = 0; gg2 < 4; ++gg2) {
            int col = 512 * gg2 + j0 + jj;
            vg[gg2] = smem[gg2 * 1024 + idx] + smem[(4 + gg2) * 1024 + idx]
                    + C_h[(size_t)b * 4608 + 2560 + col]
                    + b_ih[col] + b_hh[col];
        }
        float i_ = sigf(vg[0]), f_ = sigf(vg[1]), gt = tanhf(vg[2]), o_ = sigf(vg[3]);
        int cidx = b * 512 + j0 + jj;
        float cn = f_ * cbuf[cidx] + i_ * gt;
        cbuf[cidx] = cn;
        __hip_bfloat16 hb = __float2bfloat16(o_ * tanhf(cn));
        hbuf[cidx] = hb;
        hstore[(size_t)t * (64 * 512) + cidx] = hb;
    }
}

// Per-phase kernels
__global__ __launch_bounds__(256) void p1_kernel(
    const __hip_bfloat16* hbuf, const __hip_bfloat16* Wb_bet,
    const __hip_bfloat16* Wb_dec, const __hip_bfloat16* Wb_hh, float* C_h) {
    phase1(blockIdx.x, threadIdx.x, hbuf, Wb_bet, Wb_dec, Wb_hh, C_h);
}
__global__ __launch_bounds__(256) void p2_kernel(
    const __hip_bfloat16* att1, const __hip_bfloat16* enc_s, const float* C_h,
    const float* w_full, const float* b_full, const float* b_dec,
    const float* b_beta, const int* dec_lens,
    __hip_bfloat16* awebuf, float* out_alphas, int t) {
    __shared__ float smem[4096];
    phase2(blockIdx.x, threadIdx.x, smem, att1, enc_s, C_h, w_full, b_full,
           b_dec, b_beta, dec_lens, awebuf, out_alphas, t);
}
__global__ __launch_bounds__(512) void p3_kernel(
    const __hip_bfloat16* awebuf, const __hip_bfloat16* embs_all,
    const __hip_bfloat16* Wb_ih, const float* C_h,
    const float* b_ih, const float* b_hh,
    float* cbuf, __hip_bfloat16* hbuf, __hip_bfloat16* hstore, int t) {
    __shared__ float smem[8192];
    phase3(blockIdx.x, threadIdx.x, smem, awebuf, embs_all, Wb_ih, C_h,
           b_ih, b_hh, cbuf, hbuf, hstore, t);
}

// ===========================================================================
// Init-phase kernels
// ===========================================================================
__global__ void sort_kernel(const int* __restrict__ cap_len,
                            const int* __restrict__ caps,
                            int* __restrict__ sort_ind,
                            int* __restrict__ dec_lens,
                            int* __restrict__ caps_s,
                            float* __restrict__ out_caps,
                            float* __restrict__ out_dlen,
                            float* __restrict__ out_sind) {
    int i = threadIdx.x;  // 64 threads
    __shared__ int len[BDIM];
    len[i] = cap_len[i];
    __syncthreads();
    int li = len[i];
    int r = 0;
    for (int j = 0; j < BDIM; ++j) {
        int lj = len[j];
        if (lj > li || (lj == li && j < i)) ++r;
    }
    sort_ind[r] = i;
    dec_lens[r] = li - 1;
    out_sind[r] = (float)i;
    out_dlen[r] = (float)(li - 1);
    for (int tt = 0; tt < LCAP; ++tt) {
        int v = caps[i * LCAP + tt];
        caps_s[r * LCAP + tt] = v;
        out_caps[r * LCAP + tt] = (float)v;
    }
}

__global__ __launch_bounds__(256) void conv_enc_kernel(const float* __restrict__ enc,
                                                       const int* __restrict__ sort_ind,
                                                       __hip_bfloat16* __restrict__ enc_s,
                                                       float* __restrict__ mean_enc) {
    int b = blockIdx.y, tid = threadIdx.x;
    int e = (blockIdx.x << 8) + tid;
    const float* ep = enc + (size_t)sort_ind[b] * (PDIM * ENC) + e;
    __hip_bfloat16* op = enc_s + (size_t)b * (PDIM * ENC) + e;
    float s = 0.f;
    for (int p = 0; p < PDIM; ++p) {
        float v = ep[(size_t)p * ENC];
        s += v;
        op[(size_t)p * ENC] = __float2bfloat16(v);
    }
    mean_enc[(size_t)b * ENC + e] = s * (1.0f / (float)PDIM);
}

__global__ __launch_bounds__(256) void f2b_kernel(const float* __restrict__ src,
                                                  __hip_bfloat16* __restrict__ dst, int n) {
    int i = blockIdx.x * 256 + threadIdx.x;
    if (i < n) dst[i] = __float2bfloat16(src[i]);
}

__global__ __launch_bounds__(256) void h0b_kernel(const float* __restrict__ h0f,
                                                  __hip_bfloat16* __restrict__ hbuf) {
    int idx = blockIdx.x * 256 + threadIdx.x;  // < 64*512
    hbuf[idx] = __float2bfloat16(h0f[idx]);
}

__global__ __launch_bounds__(256) void embgather_kernel(
    const float* __restrict__ emb_table, const int* __restrict__ caps_s,
    __hip_bfloat16* __restrict__ embs_all) {
    int b = blockIdx.x, t = blockIdx.y;
    int cap = caps_s[b * LCAP + t];
    int j = threadIdx.x << 1;
    float2 e = *(const float2*)(emb_table + (size_t)cap * EMBD + j);
    __hip_bfloat16 eb[2];
    eb[0] = __float2bfloat16(e.x); eb[1] = __float2bfloat16(e.y);
    *(uint*)(embs_all + ((size_t)t * 64 + b) * 512 + j) = *(uint*)eb;
}

__global__ __launch_bounds__(256) void gemm32_k(
    const float* __restrict__ A, int lda,
    const float* __restrict__ W0, const float* __restrict__ bias0,
    float* __restrict__ C, int ldc, int K) {
    __shared__ float As[16][64];
    __shared__ float Ws[16][64];
    const int tid = threadIdx.x;
    const int tx = tid & 15, ty = tid >> 4;
    const int bn0 = blockIdx.x * 64;
    const int lr = tid >> 2;
    const int lk = (tid & 3) << 2;
    const float* Arow = A + (size_t)lr * lda;
    const int wn = bn0 + lr;
    float acc[4][4];
#pragma unroll
    for (int i = 0; i < 4; ++i)
#pragma unroll
        for (int j = 0; j < 4; ++j) acc[i][j] = 0.f;
    for (int k0 = 0; k0 < K; k0 += 16) {
        float4 av = *(const float4*)(Arow + k0 + lk);
        float4 wv = *(const float4*)(W0 + (size_t)wn * K + k0 + lk);
        __syncthreads();
        As[lk + 0][lr] = av.x; As[lk + 1][lr] = av.y;
        As[lk + 2][lr] = av.z; As[lk + 3][lr] = av.w;
        Ws[lk + 0][lr] = wv.x; Ws[lk + 1][lr] = wv.y;
        Ws[lk + 2][lr] = wv.z; Ws[lk + 3][lr] = wv.w;
        __syncthreads();
#pragma unroll
        for (int kk = 0; kk < 16; ++kk) {
            const float4 a = *(const float4*)&As[kk][ty << 2];
            const float4 w = *(const float4*)&Ws[kk][tx << 2];
            acc[0][0] += a.x * w.x; acc[0][1] += a.x * w.y; acc[0][2] += a.x * w.z; acc[0][3] += a.x * w.w;
            acc[1][0] += a.y * w.x; acc[1][1] += a.y * w.y; acc[1][2] += a.y * w.z; acc[1][3] += a.y * w.w;
            acc[2][0] += a.z * w.x; acc[2][1] += a.z * w.y; acc[2][2] += a.z * w.z; acc[2][3] += a.z * w.w;
            acc[3][0] += a.w * w.x; acc[3][1] += a.w * w.y; acc[3][2] += a.w * w.z; acc[3][3] += a.w * w.w;
        }
    }
#pragma unroll
    for (int i = 0; i < 4; ++i) {
        int row = (ty << 2) + i;
#pragma unroll
        for (int j = 0; j < 4; ++j) {
            int col = bn0 + (tx << 2) + j;
            C[(size_t)row * ldc + col] = acc[i][j] + bias0[col];
        }
    }
}

// att1 = enc_s @ W_enc^T + b_enc -> bf16. grid (104, 8), 104 % 8 == 0 so all
// 8 n-blocks of an m-panel land on XCD bx%8 (L2 co-location). 4 waves/block,
// wave = 32-row subtile (MF=2), shared 64-col n-tile. bx >= 98 exits.
__global__ __launch_bounds__(256) void att1_gemm(
    const __hip_bfloat16* __restrict__ A, const __hip_bfloat16* __restrict__ W,
    const float* __restrict__ bias, __hip_bfloat16* __restrict__ C) {
    const int bx = blockIdx.x;
    if (bx >= 98) return;
    const int tid = threadIdx.x;
    const int l = tid & 63, c16 = l & 15, kg = l >> 4, w = tid >> 6;
    const int m0 = bx * 128 + w * 32, n0 = blockIdx.y * 64;
    f4v acc[2][4];
#pragma unroll
    for (int mi = 0; mi < 2; ++mi)
#pragma unroll
        for (int ni = 0; ni < 4; ++ni) acc[mi][ni] = (f4v)0.0f;
    const __hip_bfloat16* arow[2];
#pragma unroll
    for (int mi = 0; mi < 2; ++mi)
        arow[mi] = A + (size_t)(m0 + mi * 16 + c16) * ENC + kg * 8;
    const __hip_bfloat16* wrow[4];
#pragma unroll
    for (int ni = 0; ni < 4; ++ni)
        wrow[ni] = W + (size_t)(n0 + ni * 16 + c16) * ENC + kg * 8;
    gemm_seg<2, 4, 64>(arow, wrow, acc);
#pragma unroll
    for (int mi = 0; mi < 2; ++mi)
#pragma unroll
        for (int ni = 0; ni < 4; ++ni)
#pragma unroll
            for (int i = 0; i < 4; ++i) {
                int r = m0 + mi * 16 + kg * 4 + i;
                int c = n0 + ni * 16 + c16;
                C[(size_t)r * 512 + c] = __float2bfloat16(acc[mi][ni][i] + bias[c]);
            }
}

__global__ __launch_bounds__(64) void predsb_gemm(
    const __hip_bfloat16* __restrict__ Hs,   // [1856][512]
    const __hip_bfloat16* __restrict__ Wfc,  // [10000][512]
    const float* __restrict__ bias,
    const int* __restrict__ dec_lens,
    float* __restrict__ out) {
    const int l = threadIdx.x, c16 = l & 15, kg = l >> 4;
    const int n0 = blockIdx.x * 64, m0 = blockIdx.y * 32;
    f4v acc[2][4];
#pragma unroll
    for (int mi = 0; mi < 2; ++mi)
#pragma unroll
        for (int ni = 0; ni < 4; ++ni) acc[mi][ni] = (f4v)0.0f;
    const __hip_bfloat16* arow[2];
#pragma unroll
    for (int mi = 0; mi < 2; ++mi)
        arow[mi] = Hs + (size_t)(m0 + mi * 16 + c16) * 512 + kg * 8;
    const __hip_bfloat16* wrow[4];
#pragma unroll
    for (int ni = 0; ni < 4; ++ni) {
        int n = n0 + ni * 16 + c16;
        int nn = (n < VOC) ? n : (VOC - 1);
        wrow[ni] = Wfc + (size_t)nn * 512 + kg * 8;
    }
    gemm_seg<2, 4, 16>(arow, wrow, acc);
#pragma unroll
    for (int mi = 0; mi < 2; ++mi)
#pragma unroll
        for (int ni = 0; ni < 4; ++ni)
#pragma unroll
            for (int i = 0; i < 4; ++i) {
                int r = m0 + mi * 16 + kg * 4 + i;
                int c = n0 + ni * 16 + c16;
                if (c < VOC) {
                    int tt = r >> 6, b = r & 63;
                    float v = acc[mi][ni][i] + bias[c];
                    out[(size_t)b * (TSTEPS * VOC) + (size_t)tt * VOC + c] =
                        (tt < dec_lens[b]) ? v : 0.f;
                }
            }
}

// ---------------------------------------------------------------------------
extern "C" void kernel_launch(void* const* d_in, const int* in_sizes, int n_in,
                              void* d_out, int out_size, void* d_ws, size_t ws_size,
                              hipStream_t stream) {
    const float* enc      = (const float*)d_in[0];
    const int*   caps     = (const int*)d_in[1];
    const int*   clen     = (const int*)d_in[2];
    const float* W_enc    = (const float*)d_in[3];
    const float* b_enc    = (const float*)d_in[4];
    const float* W_dec    = (const float*)d_in[5];
    const float* b_dec    = (const float*)d_in[6];
    const float* w_full   = (const float*)d_in[7];
    const float* b_full   = (const float*)d_in[8];
    const float* emb_tab  = (const float*)d_in[9];
    const float* W_ih     = (const float*)d_in[10];
    const float* b_ih     = (const float*)d_in[11];
    const float* W_hh     = (const float*)d_in[12];
    const float* b_hh     = (const float*)d_in[13];
    const float* W_init_h = (const float*)d_in[14];
    const float* b_init_h = (const float*)d_in[15];
    const float* W_init_c = (const float*)d_in[16];
    const float* b_init_c = (const float*)d_in[17];
    const float* W_beta   = (const float*)d_in[18];
    const float* b_beta   = (const float*)d_in[19];
    const float* W_fc     = (const float*)d_in[20];
    const float* b_fc     = (const float*)d_in[21];

    float* out_pred = (float*)d_out;
    float* out_alph = out_pred + (size_t)BDIM * TSTEPS * VOC;
    float* out_caps = out_alph + (size_t)BDIM * TSTEPS * PDIM;
    float* out_dlen = out_caps + BDIM * LCAP;
    float* out_sind = out_dlen + BDIM;

    // ---- workspace carve-up (256B aligned) ----
    char* p = (char*)d_ws;
    auto carve = [&](size_t bytes) { char* r = p; p += (bytes + 255) & ~(size_t)255; return r; };
    int* sort_ind = (int*)carve(64 * 4);
    int* dec_lens = (int*)carve(64 * 4);
    int* caps_s   = (int*)carve(64 * LCAP * 4);
    float* cbuf   = (float*)carve((size_t)64 * 512 * 4);
    float* C_h    = (float*)carve((size_t)64 * 4608 * 4);
    float* mean_e = (float*)carve((size_t)64 * ENC * 4);
    float* h0f    = (float*)carve((size_t)64 * 512 * 4);
    __hip_bfloat16* hbuf   = (__hip_bfloat16*)carve((size_t)64 * 512 * 2);
    __hip_bfloat16* awebuf = (__hip_bfloat16*)carve((size_t)64 * 2048 * 2);
    __hip_bfloat16* hstore = (__hip_bfloat16*)carve((size_t)TSTEPS * 64 * 512 * 2);
    __hip_bfloat16* enc_s  = (__hip_bfloat16*)carve((size_t)64 * PDIM * ENC * 2);
    __hip_bfloat16* att1   = (__hip_bfloat16*)carve((size_t)64 * PDIM * 512 * 2);
    __hip_bfloat16* Wb_enc = (__hip_bfloat16*)carve((size_t)512 * 2048 * 2);
    __hip_bfloat16* Wb_bet = (__hip_bfloat16*)carve((size_t)2048 * 512 * 2);
    __hip_bfloat16* Wb_dec = (__hip_bfloat16*)carve((size_t)512 * 512 * 2);
    __hip_bfloat16* Wb_ih  = (__hip_bfloat16*)carve((size_t)2048 * 2560 * 2);
    __hip_bfloat16* Wb_hh  = (__hip_bfloat16*)carve((size_t)2048 * 512 * 2);
    __hip_bfloat16* Wb_fc  = (__hip_bfloat16*)carve((size_t)VOC * 512 * 2);
    // embs_all aliases Wb_enc (written after att1_gemm's last read of Wb_enc)
    __hip_bfloat16* embs_all = Wb_enc;   // 1.81MB <= 2MB

    // ---- init phase ----
    sort_kernel<<<1, 64, 0, stream>>>(clen, caps, sort_ind, dec_lens, caps_s,
                                      out_caps, out_dlen, out_sind);
    conv_enc_kernel<<<dim3(8, 64), 256, 0, stream>>>(enc, sort_ind, enc_s, mean_e);
    f2b_kernel<<<(512 * 2048 + 255) / 256, 256, 0, stream>>>(W_enc, Wb_enc, 512 * 2048);
    f2b_kernel<<<(2048 * 512 + 255) / 256, 256, 0, stream>>>(W_beta, Wb_bet, 2048 * 512);
    f2b_kernel<<<(512 * 512 + 255) / 256, 256, 0, stream>>>(W_dec, Wb_dec, 512 * 512);
    f2b_kernel<<<(2048 * 2560 + 255) / 256, 256, 0, stream>>>(W_ih, Wb_ih, 2048 * 2560);
    f2b_kernel<<<(2048 * 512 + 255) / 256, 256, 0, stream>>>(W_hh, Wb_hh, 2048 * 512);
    f2b_kernel<<<(VOC * 512 + 255) / 256, 256, 0, stream>>>(W_fc, Wb_fc, VOC * 512);

    gemm32_k<<<dim3(8, 1), 256, 0, stream>>>(mean_e, ENC, W_init_h, b_init_h, h0f, 512, ENC);
    gemm32_k<<<dim3(8, 1), 256, 0, stream>>>(mean_e, ENC, W_init_c, b_init_c, cbuf, 512, ENC);
    h0b_kernel<<<128, 256, 0, stream>>>(h0f, hbuf);

    // att1 (M=12544, N=512, K=2048) -> bf16 (last reader of Wb_enc)
    att1_gemm<<<dim3(104, 8), 256, 0, stream>>>(enc_s, Wb_enc, b_enc, att1);

    // embs_all (aliases Wb_enc; safe after att1_gemm)
    embgather_kernel<<<dim3(64, TSTEPS), 256, 0, stream>>>(emb_tab, caps_s, embs_all);

    // ---- decode loop: 3 regular launches per step ----
    for (int t = 0; t < TSTEPS; ++t) {
        p1_kernel<<<72, 256, 0, stream>>>(hbuf, Wb_bet, Wb_dec, Wb_hh, C_h);
        p2_kernel<<<256, 256, 0, stream>>>(att1, enc_s, C_h, w_full, b_full,
                                           b_dec, b_beta, dec_lens, awebuf,
                                           out_alph, t);
        p3_kernel<<<32, 512, 0, stream>>>(awebuf, embs_all, Wb_ih, C_h,
                                          b_ih, b_hh, cbuf, hbuf, hstore, t);
    }

    // batched preds over all timesteps (M=1856, N=10000, K=512)
    predsb_gemm<<<dim3(160, 58), 64, 0, stream>>>(hstore, Wb_fc, b_fc, dec_lens, out_pred);
}